// Round 1
// baseline (2334.976 us; speedup 1.0000x reference)
//
#include <hip/hip_runtime.h>

#define NN 50000
#define NE 1600000
#define NR 8
#define D 128
#define DOUT 64
#define NBINS (NR * NN)               // 400000
#define SCAN_BS 1024
#define SCAN_NB ((NBINS + SCAN_BS - 1) / SCAN_BS)   // 391

// ---------------- CSR build ----------------

__global__ void k_hist(const int* __restrict__ ei, const int* __restrict__ et,
                       int* __restrict__ cnt) {
    int e = blockIdx.x * blockDim.x + threadIdx.x;
    if (e < NE) {
        int dst = ei[NE + e];
        int t = et[e];
        atomicAdd(&cnt[t * NN + dst], 1);
    }
}

__global__ __launch_bounds__(SCAN_BS)
void k_scan_a(const int* __restrict__ cnt, int* __restrict__ off,
              int* __restrict__ bsum) {
    __shared__ int s[SCAN_BS];
    int t = threadIdx.x;
    int i = blockIdx.x * SCAN_BS + t;
    int v = (i < NBINS) ? cnt[i] : 0;
    s[t] = v;
    __syncthreads();
    for (int o = 1; o < SCAN_BS; o <<= 1) {
        int x = (t >= o) ? s[t - o] : 0;
        __syncthreads();
        s[t] += x;
        __syncthreads();
    }
    if (i < NBINS) off[i] = s[t] - v;           // exclusive
    if (t == SCAN_BS - 1) bsum[blockIdx.x] = s[t];
}

__global__ __launch_bounds__(512)
void k_scan_b(const int* __restrict__ bsum, int* __restrict__ bexc) {
    __shared__ int s[512];
    int t = threadIdx.x;
    int v = (t < SCAN_NB) ? bsum[t] : 0;
    s[t] = v;
    __syncthreads();
    for (int o = 1; o < 512; o <<= 1) {
        int x = (t >= o) ? s[t - o] : 0;
        __syncthreads();
        s[t] += x;
        __syncthreads();
    }
    if (t < SCAN_NB) bexc[t] = s[t] - v;
}

__global__ __launch_bounds__(SCAN_BS)
void k_scan_c(int* __restrict__ off, const int* __restrict__ bexc) {
    int t = threadIdx.x;
    int i = blockIdx.x * SCAN_BS + t;
    if (i < NBINS) off[i] += bexc[blockIdx.x];
    if (i == 0) off[NBINS] = NE;
}

__global__ void k_scatter(const int* __restrict__ ei, const int* __restrict__ et,
                          int* __restrict__ cursor, int* __restrict__ esrc) {
    int e = blockIdx.x * blockDim.x + threadIdx.x;
    if (e < NE) {
        int k = et[e] * NN + ei[NE + e];
        int p = atomicAdd(&cursor[k], 1);
        esrc[p] = ei[e];
    }
}

__global__ void k_invdeg(const int* __restrict__ cnt, float* __restrict__ invdeg) {
    int v = blockIdx.x * blockDim.x + threadIdx.x;
    if (v < NN) {
        int s = 0;
        #pragma unroll
        for (int r = 0; r < NR; ++r) s += cnt[r * NN + v];
        invdeg[v] = 1.0f / (float)max(s, 1);
    }
}

// ---------------- aggregation (atomic-free via CSR) ----------------
// Y[v][d] = sum over edges with rel in [r0,r1], dst==v of X[src][d]
// (optionally scaled by invdeg[v])
__global__ __launch_bounds__(128)
void k_agg(const float* __restrict__ X, float* __restrict__ Y,
           const int* __restrict__ off, const int* __restrict__ esrc,
           const float* __restrict__ invdeg, int r0, int r1, int scale) {
    int v = blockIdx.x;
    int d = threadIdx.x;
    float acc = 0.f;
    for (int r = r0; r <= r1; ++r) {
        int s = off[r * NN + v];
        int e = off[r * NN + v + 1];
        for (int j = s; j < e; ++j) {
            acc += X[(size_t)esrc[j] * D + d];
        }
    }
    if (scale) acc *= invdeg[v];
    Y[(size_t)v * D + d] = acc;
}

// ---------------- fp32 GEMM  Y[M,NC] (op)= X[M,128] @ W[128,NC] ----------------
// mode 0: Y = acc
// mode 1: Y += acc
// mode 2: Y = aux + alpha*(acc + bias)
// mode 3: Y = acc + bias
template <int NC>
__global__ __launch_bounds__(384)
void k_gemm(const float* __restrict__ X, const float* __restrict__ W,
            float* __restrict__ Y, const float* __restrict__ aux,
            const float* __restrict__ bias, const float* __restrict__ alpha_p,
            int mode) {
    constexpr int CG = NC / 8;       // col groups (each thread: 2 x float4 cols)
    constexpr int RG = 384 / CG;     // row groups
    constexpr int MT = RG * 4;       // rows per block
    constexpr int LDX = D + 4;       // pad: a-read stride 528 floats -> banks +16 (2-way, free)
    __shared__ float Xs[MT * LDX];
    __shared__ float Ws[D * NC];

    const int tid = threadIdx.x;
    const int row0 = blockIdx.x * MT;

    // stage X tile (guarded, zero-fill)
    for (int i = tid; i < MT * (D / 4); i += 384) {
        int r = i >> 5;
        int c4 = (i & 31) * 4;
        float4 v = make_float4(0.f, 0.f, 0.f, 0.f);
        int gr = row0 + r;
        if (gr < NN) v = *reinterpret_cast<const float4*>(X + (size_t)gr * D + c4);
        *reinterpret_cast<float4*>(&Xs[r * LDX + c4]) = v;
    }
    // stage W
    for (int i = tid; i < D * (NC / 4); i += 384) {
        int r = i / (NC / 4);
        int c4 = (i % (NC / 4)) * 4;
        *reinterpret_cast<float4*>(&Ws[r * NC + c4]) =
            *reinterpret_cast<const float4*>(W + r * NC + c4);
    }
    __syncthreads();

    const int cx = tid % CG;
    const int ry = tid / CG;
    const int c0 = cx * 4;
    const int c1 = NC / 2 + cx * 4;   // split halves: b128 lanes stride 16B -> 2-way max

    float acc[4][8];
    #pragma unroll
    for (int i = 0; i < 4; ++i)
        #pragma unroll
        for (int j = 0; j < 8; ++j) acc[i][j] = 0.f;

    #pragma unroll 4
    for (int k = 0; k < D; ++k) {
        float4 w0 = *reinterpret_cast<const float4*>(&Ws[k * NC + c0]);
        float4 w1 = *reinterpret_cast<const float4*>(&Ws[k * NC + c1]);
        #pragma unroll
        for (int i = 0; i < 4; ++i) {
            float a = Xs[(ry * 4 + i) * LDX + k];
            acc[i][0] += a * w0.x; acc[i][1] += a * w0.y;
            acc[i][2] += a * w0.z; acc[i][3] += a * w0.w;
            acc[i][4] += a * w1.x; acc[i][5] += a * w1.y;
            acc[i][6] += a * w1.z; acc[i][7] += a * w1.w;
        }
    }

    float al = (mode == 2) ? *alpha_p : 0.f;
    float4 b0 = make_float4(0.f, 0.f, 0.f, 0.f), b1 = b0;
    if (mode >= 2) {
        b0 = *reinterpret_cast<const float4*>(bias + c0);
        b1 = *reinterpret_cast<const float4*>(bias + c1);
    }

    #pragma unroll
    for (int i = 0; i < 4; ++i) {
        int gr = row0 + ry * 4 + i;
        if (gr >= NN) continue;
        float* yp0 = Y + (size_t)gr * NC + c0;
        float* yp1 = Y + (size_t)gr * NC + c1;
        float4 r0v = make_float4(acc[i][0], acc[i][1], acc[i][2], acc[i][3]);
        float4 r1v = make_float4(acc[i][4], acc[i][5], acc[i][6], acc[i][7]);
        if (mode == 0) {
            *reinterpret_cast<float4*>(yp0) = r0v;
            *reinterpret_cast<float4*>(yp1) = r1v;
        } else if (mode == 1) {
            float4 y0 = *reinterpret_cast<const float4*>(yp0);
            float4 y1 = *reinterpret_cast<const float4*>(yp1);
            y0.x += r0v.x; y0.y += r0v.y; y0.z += r0v.z; y0.w += r0v.w;
            y1.x += r1v.x; y1.y += r1v.y; y1.z += r1v.z; y1.w += r1v.w;
            *reinterpret_cast<float4*>(yp0) = y0;
            *reinterpret_cast<float4*>(yp1) = y1;
        } else if (mode == 2) {
            float4 a0 = *reinterpret_cast<const float4*>(aux + (size_t)gr * NC + c0);
            float4 a1 = *reinterpret_cast<const float4*>(aux + (size_t)gr * NC + c1);
            float4 y0, y1;
            y0.x = a0.x + al * (r0v.x + b0.x); y0.y = a0.y + al * (r0v.y + b0.y);
            y0.z = a0.z + al * (r0v.z + b0.z); y0.w = a0.w + al * (r0v.w + b0.w);
            y1.x = a1.x + al * (r1v.x + b1.x); y1.y = a1.y + al * (r1v.y + b1.y);
            y1.z = a1.z + al * (r1v.z + b1.z); y1.w = a1.w + al * (r1v.w + b1.w);
            *reinterpret_cast<float4*>(yp0) = y0;
            *reinterpret_cast<float4*>(yp1) = y1;
        } else {
            float4 y0 = make_float4(r0v.x + b0.x, r0v.y + b0.y, r0v.z + b0.z, r0v.w + b0.w);
            float4 y1 = make_float4(r1v.x + b1.x, r1v.y + b1.y, r1v.z + b1.z, r1v.w + b1.w);
            *reinterpret_cast<float4*>(yp0) = y0;
            *reinterpret_cast<float4*>(yp1) = y1;
        }
    }
}

// ---------------- elementwise: Y = relu(X * invdeg[node]) ----------------
__global__ void k_relu_scale(const float* __restrict__ Xin, float* __restrict__ Yout,
                             const float* __restrict__ invdeg) {
    int i = blockIdx.x * blockDim.x + threadIdx.x;   // float4 index
    if (i < NN * (D / 4)) {
        int v = i / (D / 4);
        float s = invdeg[v];
        float4 x = reinterpret_cast<const float4*>(Xin)[i];
        float4 y;
        y.x = fmaxf(x.x * s, 0.f);
        y.y = fmaxf(x.y * s, 0.f);
        y.z = fmaxf(x.z * s, 0.f);
        y.w = fmaxf(x.w * s, 0.f);
        reinterpret_cast<float4*>(Yout)[i] = y;
    }
}

// ---------------- launch ----------------

extern "C" void kernel_launch(void* const* d_in, const int* in_sizes, int n_in,
                              void* d_out, int out_size, void* d_ws, size_t ws_size,
                              hipStream_t stream) {
    const float* X   = (const float*)d_in[0];
    const int*   ei  = (const int*)d_in[1];
    const int*   et  = (const int*)d_in[2];
    const float* W1  = (const float*)d_in[3];
    const float* W01 = (const float*)d_in[4];
    const float* al1 = (const float*)d_in[5];
    const float* p1w = (const float*)d_in[6];
    const float* p1b = (const float*)d_in[7];
    const float* W2  = (const float*)d_in[8];
    const float* W02 = (const float*)d_in[9];
    const float* al2 = (const float*)d_in[10];
    const float* p2w = (const float*)d_in[11];
    const float* p2b = (const float*)d_in[12];
    const float* ow  = (const float*)d_in[13];
    const float* ob  = (const float*)d_in[14];
    float* out = (float*)d_out;

    char* wsp = (char*)d_ws;
    size_t o = 0;
    auto take = [&](size_t bytes) -> void* {
        void* p = wsp + o;
        o = (o + bytes + 255) & ~(size_t)255;
        return p;
    };
    int*   cnt    = (int*)take((size_t)NBINS * 4);
    int*   off    = (int*)take((size_t)(NBINS + 1) * 4);
    int*   cursor = (int*)take((size_t)NBINS * 4);
    int*   bsum   = (int*)take(512 * 4);
    int*   bexc   = (int*)take(512 * 4);
    float* invdeg = (float*)take((size_t)NN * 4);
    int*   esrc   = (int*)take((size_t)NE * 4);
    float* A      = (float*)take((size_t)NN * D * 4);
    float* B1     = (float*)take((size_t)NN * D * 4);
    float* B2     = (float*)take((size_t)NN * D * 4);
    if (o > ws_size) return;   // deterministic guard

    const int GRID128 = (NN + 95) / 96;     // 521
    const int GRID64  = (NN + 191) / 192;   // 261

    // CSR build
    hipMemsetAsync(cnt, 0, (size_t)NBINS * 4, stream);
    k_hist<<<(NE + 255) / 256, 256, 0, stream>>>(ei, et, cnt);
    k_scan_a<<<SCAN_NB, SCAN_BS, 0, stream>>>(cnt, off, bsum);
    k_scan_b<<<1, 512, 0, stream>>>(bsum, bexc);
    k_scan_c<<<SCAN_NB, SCAN_BS, 0, stream>>>(off, bexc);
    hipMemcpyAsync(cursor, off, (size_t)NBINS * 4, hipMemcpyDeviceToDevice, stream);
    k_scatter<<<(NE + 255) / 256, 256, 0, stream>>>(ei, et, cursor, esrc);
    k_invdeg<<<(NN + 255) / 256, 256, 0, stream>>>(cnt, invdeg);

    // ---- layer 1: rgcn ----
    k_gemm<D><<<GRID128, 384, 0, stream>>>(X, W01, B1, nullptr, nullptr, nullptr, 0);
    for (int r = 0; r < NR; ++r) {
        k_agg<<<NN, 128, 0, stream>>>(X, A, off, esrc, invdeg, r, r, 0);
        k_gemm<D><<<GRID128, 384, 0, stream>>>(A, W1 + (size_t)r * D * D, B1,
                                               nullptr, nullptr, nullptr, 1);
    }
    k_relu_scale<<<(NN * (D / 4) + 255) / 256, 256, 0, stream>>>(B1, B2, invdeg);  // B2 = h1

    // ---- layer 1: group ----
    k_agg<<<NN, 128, 0, stream>>>(B2, A, off, esrc, invdeg, 0, NR - 1, 1);
    k_gemm<D><<<GRID128, 384, 0, stream>>>(A, p1w, B1, B2, p1b, al1, 2);  // B1 = g1

    // ---- layer 2: rgcn ----
    k_gemm<D><<<GRID128, 384, 0, stream>>>(B1, W02, B2, nullptr, nullptr, nullptr, 0);
    for (int r = 0; r < NR; ++r) {
        k_agg<<<NN, 128, 0, stream>>>(B1, A, off, esrc, invdeg, r, r, 0);
        k_gemm<D><<<GRID128, 384, 0, stream>>>(A, W2 + (size_t)r * D * D, B2,
                                               nullptr, nullptr, nullptr, 1);
    }
    k_relu_scale<<<(NN * (D / 4) + 255) / 256, 256, 0, stream>>>(B2, B2, invdeg);  // B2 = h2

    // ---- layer 2: group ----
    k_agg<<<NN, 128, 0, stream>>>(B2, A, off, esrc, invdeg, 0, NR - 1, 1);
    k_gemm<D><<<GRID128, 384, 0, stream>>>(A, p2w, B1, B2, p2b, al2, 2);  // B1 = g2

    // ---- final projection ----
    k_gemm<DOUT><<<GRID64, 384, 0, stream>>>(B1, ow, out, nullptr, ob, nullptr, 3);
}

// Round 2
// 843.680 us; speedup vs baseline: 2.7676x; 2.7676x over previous
//
#include <hip/hip_runtime.h>
#include <hip/hip_bf16.h>

#define NN 50000
#define NE 1600000
#define NR 8
#define D 128
#define DOUT 64
#define NBINS (NR * NN)               // 400000, keyed dst*8 + rel
#define SCAN_BS 1024
#define SCAN_NB ((NBINS + SCAN_BS - 1) / SCAN_BS)   // 391
#define GRIDM ((NN + 127) / 128)      // 391 M-tiles for MFMA GEMM

typedef __attribute__((ext_vector_type(8))) __bf16 bf16x8;
typedef __attribute__((ext_vector_type(4))) float f32x4;

__device__ __forceinline__ float bflo(unsigned u) { return __uint_as_float(u << 16); }
__device__ __forceinline__ float bfhi(unsigned u) { return __uint_as_float(u & 0xffff0000u); }
__device__ __forceinline__ unsigned f2bf_rne(float x) {
    unsigned u = __float_as_uint(x);
    return (u + 0x7fffu + ((u >> 16) & 1u)) >> 16;
}
__device__ __forceinline__ unsigned pack2(float a, float b) {
    return f2bf_rne(a) | (f2bf_rne(b) << 16);
}

// ---------------- CSR build (key = dst*8 + rel) ----------------

__global__ void k_hist(const int* __restrict__ ei, const int* __restrict__ et,
                       int* __restrict__ cnt) {
    int e = blockIdx.x * blockDim.x + threadIdx.x;
    if (e < NE) atomicAdd(&cnt[ei[NE + e] * NR + et[e]], 1);
}

__global__ __launch_bounds__(SCAN_BS)
void k_scan_a(const int* __restrict__ cnt, int* __restrict__ off,
              int* __restrict__ bsum) {
    __shared__ int s[SCAN_BS];
    int t = threadIdx.x;
    int i = blockIdx.x * SCAN_BS + t;
    int v = (i < NBINS) ? cnt[i] : 0;
    s[t] = v;
    __syncthreads();
    for (int o = 1; o < SCAN_BS; o <<= 1) {
        int x = (t >= o) ? s[t - o] : 0;
        __syncthreads();
        s[t] += x;
        __syncthreads();
    }
    if (i < NBINS) off[i] = s[t] - v;
    if (t == SCAN_BS - 1) bsum[blockIdx.x] = s[t];
}

__global__ __launch_bounds__(512)
void k_scan_b(const int* __restrict__ bsum, int* __restrict__ bexc) {
    __shared__ int s[512];
    int t = threadIdx.x;
    int v = (t < SCAN_NB) ? bsum[t] : 0;
    s[t] = v;
    __syncthreads();
    for (int o = 1; o < 512; o <<= 1) {
        int x = (t >= o) ? s[t - o] : 0;
        __syncthreads();
        s[t] += x;
        __syncthreads();
    }
    if (t < SCAN_NB) bexc[t] = s[t] - v;
}

__global__ __launch_bounds__(SCAN_BS)
void k_scan_c(int* __restrict__ off, const int* __restrict__ bexc) {
    int t = threadIdx.x;
    int i = blockIdx.x * SCAN_BS + t;
    if (i < NBINS) off[i] += bexc[blockIdx.x];
    if (i == 0) off[NBINS] = NE;
}

__global__ void k_scatter(const int* __restrict__ ei, const int* __restrict__ et,
                          int* __restrict__ cursor, int* __restrict__ esrc) {
    int e = blockIdx.x * blockDim.x + threadIdx.x;
    if (e < NE) {
        int k = ei[NE + e] * NR + et[e];
        int p = atomicAdd(&cursor[k], 1);
        esrc[p] = ei[e];
    }
}

__global__ void k_invdeg(const int* __restrict__ off, float* __restrict__ invdeg) {
    int v = blockIdx.x * blockDim.x + threadIdx.x;
    if (v < NN) {
        int deg = off[v * NR + NR] - off[v * NR];
        invdeg[v] = 1.0f / (float)max(deg, 1);
    }
}

// ---------------- prep: fp32 -> bf16 tables ----------------

// X [NN][128] f32 -> Xt [NN][64] uint (bf16 pairs)
__global__ void k_prep_x(const float* __restrict__ X, unsigned* __restrict__ Xt) {
    int i = blockIdx.x * blockDim.x + threadIdx.x;
    if (i < NN * 64) {
        float2 f = reinterpret_cast<const float2*>(X)[i];
        Xt[i] = pack2(f.x, f.y);
    }
}

// concat-transpose: dst [128][1152] bf16 ; dst[n][k] = k<128 ? W0[k][n] : Wr[(k-128)][n]
__global__ void k_prep_wcat(const float* __restrict__ W0, const float* __restrict__ Wr,
                            __hip_bfloat16* __restrict__ dst) {
    int i = blockIdx.x * blockDim.x + threadIdx.x;
    if (i < 128 * 1152) {
        int n = i / 1152, k = i % 1152;
        float v = (k < 128) ? W0[k * 128 + n] : Wr[(k - 128) * 128 + n];
        reinterpret_cast<unsigned short*>(dst)[i] = (unsigned short)f2bf_rne(v);
    }
}

// generic transpose: src [K][N] f32 -> dst [N][K] bf16
__global__ void k_prep_wt(const float* __restrict__ src, __hip_bfloat16* __restrict__ dst,
                          int K, int N) {
    int i = blockIdx.x * blockDim.x + threadIdx.x;
    if (i < N * K) {
        int n = i / K, k = i % K;
        reinterpret_cast<unsigned short*>(dst)[i] =
            (unsigned short)f2bf_rne(src[k * N + n]);
    }
}

// ---------------- aggregation (atomic-free, bf16 tables) ----------------

// wide per-relation agg: AW[v][r*64+lane] (uint = 2 bf16) = sum over rel-r in-edges
__global__ __launch_bounds__(256)
void k_aggw(const unsigned* __restrict__ Xt, unsigned* __restrict__ AW,
            const int* __restrict__ off, const int* __restrict__ esrc) {
    int wid = threadIdx.x >> 6, lane = threadIdx.x & 63;
    int v = blockIdx.x * 4 + wid;
    if (v >= NN) return;
    const int ob = v * NR;
    #pragma unroll 1
    for (int r = 0; r < NR; ++r) {
        int s = off[ob + r], e = off[ob + r + 1];
        float a0 = 0.f, a1 = 0.f;
        int j = s;
        for (; j + 4 <= e; j += 4) {
            int i0 = esrc[j], i1 = esrc[j + 1], i2 = esrc[j + 2], i3 = esrc[j + 3];
            unsigned u0 = Xt[i0 * 64 + lane], u1 = Xt[i1 * 64 + lane];
            unsigned u2 = Xt[i2 * 64 + lane], u3 = Xt[i3 * 64 + lane];
            a0 += bflo(u0) + bflo(u1) + bflo(u2) + bflo(u3);
            a1 += bfhi(u0) + bfhi(u1) + bfhi(u2) + bfhi(u3);
        }
        for (; j < e; ++j) {
            unsigned u = Xt[esrc[j] * 64 + lane];
            a0 += bflo(u); a1 += bfhi(u);
        }
        AW[(size_t)v * 512 + r * 64 + lane] = pack2(a0, a1);
    }
}

// full-graph agg with invdeg scale: AH[v][lane] = (sum over all in-edges) * invdeg
__global__ __launch_bounds__(256)
void k_aggh(const unsigned* __restrict__ Ht, unsigned* __restrict__ AH,
            const int* __restrict__ off, const int* __restrict__ esrc,
            const float* __restrict__ invdeg) {
    int wid = threadIdx.x >> 6, lane = threadIdx.x & 63;
    int v = blockIdx.x * 4 + wid;
    if (v >= NN) return;
    int s = off[v * NR], e = off[v * NR + NR];
    float a0 = 0.f, a1 = 0.f;
    int j = s;
    for (; j + 4 <= e; j += 4) {
        int i0 = esrc[j], i1 = esrc[j + 1], i2 = esrc[j + 2], i3 = esrc[j + 3];
        unsigned u0 = Ht[i0 * 64 + lane], u1 = Ht[i1 * 64 + lane];
        unsigned u2 = Ht[i2 * 64 + lane], u3 = Ht[i3 * 64 + lane];
        a0 += bflo(u0) + bflo(u1) + bflo(u2) + bflo(u3);
        a1 += bfhi(u0) + bfhi(u1) + bfhi(u2) + bfhi(u3);
    }
    for (; j < e; ++j) {
        unsigned u = Ht[esrc[j] * 64 + lane];
        a0 += bflo(u); a1 += bfhi(u);
    }
    float inv = invdeg[v];
    AH[(size_t)v * 64 + lane] = pack2(a0 * inv, a1 * inv);
}

// ---------------- bf16 MFMA GEMM, fused epilogues ----------------
// Y[M,N] = A[M,K] @ B[K,N]   (B pre-transposed: Bt [N][K] bf16)
// A: k<128 from A0 (stride 128), k>=128 from A1 (stride 1024, offset k-128)
// MODE 0 (rgcn):  v = relu(acc*invdeg[row]); Yf[row*128+col]=v; Ybf[row*128+col]=bf(v)
// MODE 1 (group): v = aux[row*128+col] + alpha*(acc + bias[col]); Ybf=bf(v)
// MODE 2 (final): Yf[row*64+col] = acc + bias[col]
template <int N, int MODE>
__global__ __launch_bounds__(256)
void k_mfma(const short* __restrict__ A0, const short* __restrict__ A1,
            const short* __restrict__ Bt, int K,
            float* __restrict__ Yf, unsigned short* __restrict__ Ybf,
            const float* __restrict__ aux, const float* __restrict__ bias,
            const float* __restrict__ alpha_p, const float* __restrict__ invdeg) {
    constexpr int NT = N / 16;
    const int w = threadIdx.x >> 6;
    const int lane = threadIdx.x & 63;
    const int lr = lane & 15;
    const int lk = (lane >> 4) * 8;
    const int rowBase = blockIdx.x * 128 + w * 32;

    const int r0 = min(rowBase + lr, NN - 1);
    const int r1 = min(rowBase + 16 + lr, NN - 1);

    f32x4 acc[2][NT];
    #pragma unroll
    for (int mi = 0; mi < 2; ++mi)
        #pragma unroll
        for (int nt = 0; nt < NT; ++nt)
            acc[mi][nt] = f32x4{0.f, 0.f, 0.f, 0.f};

    for (int k0 = 0; k0 < K; k0 += 32) {
        const short* ab; int astr, kk;
        if (k0 < 128) { ab = A0; astr = 128; kk = k0; }
        else          { ab = A1; astr = 1024; kk = k0 - 128; }
        bf16x8 a0 = *reinterpret_cast<const bf16x8*>(ab + (size_t)r0 * astr + kk + lk);
        bf16x8 a1 = *reinterpret_cast<const bf16x8*>(ab + (size_t)r1 * astr + kk + lk);
        #pragma unroll
        for (int nt = 0; nt < NT; ++nt) {
            bf16x8 b = *reinterpret_cast<const bf16x8*>(
                Bt + (size_t)(nt * 16 + lr) * K + k0 + lk);
            acc[0][nt] = __builtin_amdgcn_mfma_f32_16x16x32_bf16(a0, b, acc[0][nt], 0, 0, 0);
            acc[1][nt] = __builtin_amdgcn_mfma_f32_16x16x32_bf16(a1, b, acc[1][nt], 0, 0, 0);
        }
    }

    const float al = (MODE == 1) ? *alpha_p : 0.f;
    #pragma unroll
    for (int mi = 0; mi < 2; ++mi) {
        #pragma unroll
        for (int j = 0; j < 4; ++j) {
            const int row = rowBase + mi * 16 + (lane >> 4) * 4 + j;
            if (row >= NN) continue;
            float idg = (MODE == 0) ? invdeg[row] : 0.f;
            #pragma unroll
            for (int nt = 0; nt < NT; ++nt) {
                const int col = nt * 16 + lr;
                float v = acc[mi][nt][j];
                if (MODE == 0) {
                    v = fmaxf(v * idg, 0.f);
                    Yf[(size_t)row * 128 + col] = v;
                    Ybf[(size_t)row * 128 + col] = (unsigned short)f2bf_rne(v);
                } else if (MODE == 1) {
                    v = aux[(size_t)row * 128 + col] + al * (v + bias[col]);
                    Ybf[(size_t)row * 128 + col] = (unsigned short)f2bf_rne(v);
                } else {
                    Yf[(size_t)row * 64 + col] = v + bias[col];
                }
            }
        }
    }
}

// ---------------- launch ----------------

extern "C" void kernel_launch(void* const* d_in, const int* in_sizes, int n_in,
                              void* d_out, int out_size, void* d_ws, size_t ws_size,
                              hipStream_t stream) {
    const float* X   = (const float*)d_in[0];
    const int*   ei  = (const int*)d_in[1];
    const int*   et  = (const int*)d_in[2];
    const float* W1  = (const float*)d_in[3];
    const float* W01 = (const float*)d_in[4];
    const float* al1 = (const float*)d_in[5];
    const float* p1w = (const float*)d_in[6];
    const float* p1b = (const float*)d_in[7];
    const float* W2  = (const float*)d_in[8];
    const float* W02 = (const float*)d_in[9];
    const float* al2 = (const float*)d_in[10];
    const float* p2w = (const float*)d_in[11];
    const float* p2b = (const float*)d_in[12];
    const float* ow  = (const float*)d_in[13];
    const float* ob  = (const float*)d_in[14];
    float* out = (float*)d_out;

    char* wsp = (char*)d_ws;
    size_t o = 0;
    auto take = [&](size_t bytes) -> void* {
        void* p = wsp + o;
        o = (o + bytes + 255) & ~(size_t)255;
        return p;
    };
    int*      cnt    = (int*)take((size_t)NBINS * 4);
    int*      off    = (int*)take((size_t)(NBINS + 1) * 4);
    int*      cursor = (int*)take((size_t)NBINS * 4);
    int*      bsum   = (int*)take(512 * 4);
    int*      bexc   = (int*)take(512 * 4);
    float*    invdeg = (float*)take((size_t)NN * 4);
    int*      esrc   = (int*)take((size_t)NE * 4);
    unsigned* T1     = (unsigned*)take((size_t)NN * 64 * 4);   // Xbf  -> H2bf
    unsigned* T2     = (unsigned*)take((size_t)NN * 64 * 4);   // Hbf  -> G2bf
    unsigned* T3     = (unsigned*)take((size_t)NN * 64 * 4);   // G1bf
    unsigned* AW     = (unsigned*)take((size_t)NN * 512 * 4);  // wide agg [NN][1024] bf16
    unsigned* AH     = (unsigned*)take((size_t)NN * 64 * 4);   // group agg [NN][128] bf16
    float*    Hf     = (float*)take((size_t)NN * 128 * 4);     // h f32 (residual aux)
    __hip_bfloat16* WtC1 = (__hip_bfloat16*)take((size_t)128 * 1152 * 2);
    __hip_bfloat16* WtC2 = (__hip_bfloat16*)take((size_t)128 * 1152 * 2);
    __hip_bfloat16* Wtp1 = (__hip_bfloat16*)take((size_t)128 * 128 * 2);
    __hip_bfloat16* Wtp2 = (__hip_bfloat16*)take((size_t)128 * 128 * 2);
    __hip_bfloat16* WtO  = (__hip_bfloat16*)take((size_t)64 * 128 * 2);
    if (o > ws_size) return;

    // ---- CSR build ----
    hipMemsetAsync(cnt, 0, (size_t)NBINS * 4, stream);
    k_hist<<<(NE + 255) / 256, 256, 0, stream>>>(ei, et, cnt);
    k_scan_a<<<SCAN_NB, SCAN_BS, 0, stream>>>(cnt, off, bsum);
    k_scan_b<<<1, 512, 0, stream>>>(bsum, bexc);
    k_scan_c<<<SCAN_NB, SCAN_BS, 0, stream>>>(off, bexc);
    hipMemcpyAsync(cursor, off, (size_t)NBINS * 4, hipMemcpyDeviceToDevice, stream);
    k_scatter<<<(NE + 255) / 256, 256, 0, stream>>>(ei, et, cursor, esrc);
    k_invdeg<<<(NN + 255) / 256, 256, 0, stream>>>(off, invdeg);

    // ---- prep ----
    k_prep_x<<<(NN * 64 + 255) / 256, 256, 0, stream>>>(X, T1);
    k_prep_wcat<<<(128 * 1152 + 255) / 256, 256, 0, stream>>>(W01, W1, WtC1);
    k_prep_wcat<<<(128 * 1152 + 255) / 256, 256, 0, stream>>>(W02, W2, WtC2);
    k_prep_wt<<<(128 * 128 + 255) / 256, 256, 0, stream>>>(p1w, Wtp1, 128, 128);
    k_prep_wt<<<(128 * 128 + 255) / 256, 256, 0, stream>>>(p2w, Wtp2, 128, 128);
    k_prep_wt<<<(64 * 128 + 255) / 256, 256, 0, stream>>>(ow, WtO, 128, 64);

    const int GAGG = (NN + 3) / 4;   // 12500 blocks x 256 (wave per node)

    // ---- layer 1 ----
    k_aggw<<<GAGG, 256, 0, stream>>>(T1, AW, off, esrc);
    k_mfma<128, 0><<<GRIDM, 256, 0, stream>>>(
        (const short*)T1, (const short*)AW, (const short*)WtC1, 1152,
        Hf, (unsigned short*)T2, nullptr, nullptr, nullptr, invdeg);
    k_aggh<<<GAGG, 256, 0, stream>>>(T2, AH, off, esrc, invdeg);
    k_mfma<128, 1><<<GRIDM, 256, 0, stream>>>(
        (const short*)AH, nullptr, (const short*)Wtp1, 128,
        nullptr, (unsigned short*)T3, Hf, p1b, al1, nullptr);

    // ---- layer 2 ----
    k_aggw<<<GAGG, 256, 0, stream>>>(T3, AW, off, esrc);
    k_mfma<128, 0><<<GRIDM, 256, 0, stream>>>(
        (const short*)T3, (const short*)AW, (const short*)WtC2, 1152,
        Hf, (unsigned short*)T1, nullptr, nullptr, nullptr, invdeg);
    k_aggh<<<GAGG, 256, 0, stream>>>(T1, AH, off, esrc, invdeg);
    k_mfma<128, 1><<<GRIDM, 256, 0, stream>>>(
        (const short*)AH, nullptr, (const short*)Wtp2, 128,
        nullptr, (unsigned short*)T2, Hf, p2b, al2, nullptr);

    // ---- final projection ----
    k_mfma<64, 2><<<GRIDM, 256, 0, stream>>>(
        (const short*)T2, nullptr, (const short*)WtO, 128,
        out, nullptr, nullptr, ob, nullptr, nullptr);
}